// Round 3
// baseline (2093.347 us; speedup 1.0000x reference)
//
#include <hip/hip_runtime.h>
#include <cstdint>
#include <cstddef>

#define D_DIM 256
#define T_DIM 512
#define B_DIM 128
#define S_DIM 512

typedef __attribute__((ext_vector_type(8))) short short8;
typedef __attribute__((ext_vector_type(4))) float f32x4;

// ---------- fp32 tiled GEMM (unchanged from R2): C[M,N] = A @ B^T (+biases) ----
__global__ __launch_bounds__(256, 2)
void gemm_bt(const float* __restrict__ A, const float* __restrict__ Bm,
             float* __restrict__ C,
             const float* __restrict__ bias1, const float* __restrict__ bias2,
             const int* __restrict__ ids, const float* __restrict__ emb,
             int M, int N, int K)
{
    __shared__ float As[16][128];
    __shared__ float Bs[16][128];
    const int tid = threadIdx.x;
    const int m0 = blockIdx.x * 128;
    const int n0 = blockIdx.y * 128;
    const int tx = tid & 15;
    const int ty = tid >> 4;

    float acc[8][8];
#pragma unroll
    for (int i = 0; i < 8; ++i)
#pragma unroll
        for (int j = 0; j < 8; ++j) acc[i][j] = 0.0f;

    for (int kc = 0; kc < K; kc += 16) {
#pragma unroll
        for (int p = 0; p < 2; ++p) {
            int f   = tid + p * 256;
            int row = f >> 2;
            int kq  = f & 3;
            int gm = m0 + row;
            const float* arow = ids ? (emb + (size_t)ids[gm] * K)
                                    : (A + (size_t)gm * K);
            float4 v = *(const float4*)(arow + kc + kq * 4);
            As[kq * 4 + 0][row] = v.x;
            As[kq * 4 + 1][row] = v.y;
            As[kq * 4 + 2][row] = v.z;
            As[kq * 4 + 3][row] = v.w;
            const float* brow = Bm + (size_t)(n0 + row) * K;
            float4 w = *(const float4*)(brow + kc + kq * 4);
            Bs[kq * 4 + 0][row] = w.x;
            Bs[kq * 4 + 1][row] = w.y;
            Bs[kq * 4 + 2][row] = w.z;
            Bs[kq * 4 + 3][row] = w.w;
        }
        __syncthreads();
#pragma unroll
        for (int k = 0; k < 16; ++k) {
            float a[8], b[8];
            *(float4*)&a[0] = *(const float4*)&As[k][ty * 8];
            *(float4*)&a[4] = *(const float4*)&As[k][ty * 8 + 4];
            *(float4*)&b[0] = *(const float4*)&Bs[k][tx * 8];
            *(float4*)&b[4] = *(const float4*)&Bs[k][tx * 8 + 4];
#pragma unroll
            for (int i = 0; i < 8; ++i)
#pragma unroll
                for (int j = 0; j < 8; ++j) acc[i][j] += a[i] * b[j];
        }
        __syncthreads();
    }

    float bv[8];
#pragma unroll
    for (int j = 0; j < 8; ++j) {
        int gn = n0 + tx * 8 + j;
        float v = 0.0f;
        if (bias1) v += bias1[gn];
        if (bias2) v += bias2[gn];
        bv[j] = v;
    }
#pragma unroll
    for (int i = 0; i < 8; ++i) {
        int gm = m0 + ty * 8 + i;
        float* crow = C + (size_t)gm * N + n0 + tx * 8;
        float4 v0 = make_float4(acc[i][0] + bv[0], acc[i][1] + bv[1],
                                acc[i][2] + bv[2], acc[i][3] + bv[3]);
        float4 v1 = make_float4(acc[i][4] + bv[4], acc[i][5] + bv[5],
                                acc[i][6] + bv[6], acc[i][7] + bv[7]);
        *(float4*)(crow)     = v0;
        *(float4*)(crow + 4) = v1;
    }
}

// ---------- helpers ----------
__device__ inline unsigned short f2bf(float x) {
    unsigned u = __builtin_bit_cast(unsigned, x);
    unsigned r = (u + 0x7fffu + ((u >> 16) & 1u)) >> 16;
    return (unsigned short)r;
}
__device__ inline float bf2f(unsigned short b) {
    unsigned u = ((unsigned)b) << 16;
    return __builtin_bit_cast(float, u);
}
__device__ inline float fast_tanh(float x) {
    float ax = __builtin_fabsf(x);
    float e  = __expf(-2.0f * ax);
    float r  = (1.0f - e) * __builtin_amdgcn_rcpf(1.0f + e);
    return __builtin_copysignf(r, x);
}

// ---------- MFMA Elman scan ----------
// 8 blocks x 16 batch rows (M=16 fills mfma_f32_16x16x32_bf16 exactly).
// 512 threads = 8 waves; wave w owns units [32w, 32w+32) = 2 N-tiles.
// W_hh split to bf16 hi/lo IN REGISTERS once (128 VGPRs/thread), pinned
// resident by amdgpu_waves_per_eu(2,2) (R2 lesson: launch_bounds alone only
// caps VGPRs, compiler optimized for occupancy and re-streamed W each step).
// Numerics: 3-product split (hi*hi + lo*hi + hi*lo), fp32 accum => ~2^-16 rel.
// h ping-pong in LDS, row stride 264 shorts (528 B = odd multiple of 16 B)
// => consecutive-8-lane bank groups fully spread for ds_read_b128.
#define HSTR 264
__global__ __launch_bounds__(512) __attribute__((amdgpu_waves_per_eu(2, 2)))
void rnn_scan_mfma(const float* __restrict__ pre, const float* __restrict__ Whh,
                   float* __restrict__ hout)
{
    const int tid  = threadIdx.x;
    const int wave = tid >> 6;
    const int lane = tid & 63;
    const int quad = lane >> 4;
    const int lcol = lane & 15;
    const int b0   = blockIdx.x * 16;

    __shared__ short hbuf[2][2][16][HSTR];   // [pingpong][hi/lo][row m][col k]

    // zero ping buffer 0 (h_{-1} = 0)
    for (int i = tid; i < 2 * 16 * HSTR; i += 512)
        ((short*)hbuf[0])[i] = 0;

    // --- load + split W fragments (resident for whole kernel) ---
    // B-operand layout (16x16x32): lane holds B[n=lane&15][k=quad*8+j], j=0..7
    short8 wh[2][8], wl[2][8];
#pragma unroll
    for (int tile = 0; tile < 2; ++tile) {
        const int n = wave * 32 + tile * 16 + lcol;
        const float* wr = Whh + (size_t)n * D_DIM + quad * 8;
#pragma unroll
        for (int kt = 0; kt < 8; ++kt) {
            float4 x0 = *(const float4*)(wr + kt * 32);
            float4 x1 = *(const float4*)(wr + kt * 32 + 4);
            float xs[8] = {x0.x, x0.y, x0.z, x0.w, x1.x, x1.y, x1.z, x1.w};
            short8 hi8, lo8;
#pragma unroll
            for (int j = 0; j < 8; ++j) {
                unsigned short h = f2bf(xs[j]);
                unsigned short l = f2bf(xs[j] - bf2f(h));
                hi8[j] = (short)h;
                lo8[j] = (short)l;
            }
            wh[tile][kt] = hi8;
            wl[tile][kt] = lo8;
        }
    }

    // per-lane global element offsets for pre/hout: i = tile*4 + r
    // batch row m = quad*4 + r, unit n = wave*32 + tile*16 + lcol
    unsigned preBase[8];
#pragma unroll
    for (int tile = 0; tile < 2; ++tile)
#pragma unroll
        for (int r = 0; r < 4; ++r) {
            int m = quad * 4 + r;
            int n = wave * 32 + tile * 16 + lcol;
            preBase[tile * 4 + r] = (unsigned)((b0 + m) * T_DIM) * D_DIM + n;
        }

    __syncthreads();

    const int aoff = lcol * HSTR + quad * 8;   // A-frag: lane holds A[m=lcol][k=quad*8+j]

    for (int t = 0; t < T_DIM; ++t) {
        const short* Hh = &hbuf[t & 1][0][0][0];
        const short* Hl = &hbuf[t & 1][1][0][0];
        short* Nh = &hbuf[(t + 1) & 1][0][0][0];
        short* Nl = &hbuf[(t + 1) & 1][1][0][0];

        // issue this step's pre loads; latency hidden under the MFMA phase
        float pv[8];
#pragma unroll
        for (int i = 0; i < 8; ++i)
            pv[i] = pre[(size_t)preBase[i] + (size_t)t * D_DIM];

        f32x4 acc0 = {0.f, 0.f, 0.f, 0.f};
        f32x4 acc1 = {0.f, 0.f, 0.f, 0.f};

        short8 ah = *(const short8*)(Hh + aoff);
        short8 al = *(const short8*)(Hl + aoff);
#pragma unroll
        for (int kt = 0; kt < 8; ++kt) {
            short8 ahn, aln;
            if (kt < 7) {
                ahn = *(const short8*)(Hh + aoff + (kt + 1) * 32);
                aln = *(const short8*)(Hl + aoff + (kt + 1) * 32);
            } else {
                ahn = ah; aln = al;
            }
            acc0 = __builtin_amdgcn_mfma_f32_16x16x32_bf16(ah, wh[0][kt], acc0, 0, 0, 0);
            acc1 = __builtin_amdgcn_mfma_f32_16x16x32_bf16(ah, wh[1][kt], acc1, 0, 0, 0);
            acc0 = __builtin_amdgcn_mfma_f32_16x16x32_bf16(al, wh[0][kt], acc0, 0, 0, 0);
            acc1 = __builtin_amdgcn_mfma_f32_16x16x32_bf16(al, wh[1][kt], acc1, 0, 0, 0);
            acc0 = __builtin_amdgcn_mfma_f32_16x16x32_bf16(ah, wl[0][kt], acc0, 0, 0, 0);
            acc1 = __builtin_amdgcn_mfma_f32_16x16x32_bf16(ah, wl[1][kt], acc1, 0, 0, 0);
            ah = ahn;
            al = aln;
        }

        // epilogue: C/D layout col=lane&15 (unit), row=quad*4+reg (batch)
#pragma unroll
        for (int tile = 0; tile < 2; ++tile) {
            const int n = wave * 32 + tile * 16 + lcol;
#pragma unroll
            for (int r = 0; r < 4; ++r) {
                const int m = quad * 4 + r;
                float x = (tile ? acc1[r] : acc0[r]) + pv[tile * 4 + r];
                float h = fast_tanh(x);
                hout[(size_t)preBase[tile * 4 + r] + (size_t)t * D_DIM] = h;
                unsigned short hi = f2bf(h);
                unsigned short lo = f2bf(h - bf2f(hi));
                Nh[m * HSTR + n] = (short)hi;
                Nl[m * HSTR + n] = (short)lo;
            }
        }
        __syncthreads();
    }
}

extern "C" void kernel_launch(void* const* d_in, const int* in_sizes, int n_in,
                              void* d_out, int out_size, void* d_ws, size_t ws_size,
                              hipStream_t stream)
{
    const int*   ids    = (const int*)  d_in[0];
    const float* emb    = (const float*)d_in[1];
    const float* W_ih0  = (const float*)d_in[2];
    const float* W_hh0  = (const float*)d_in[3];
    const float* b_ih0  = (const float*)d_in[4];
    const float* b_hh0  = (const float*)d_in[5];
    const float* W_ih1  = (const float*)d_in[6];
    const float* W_hh1  = (const float*)d_in[7];
    const float* b_ih1  = (const float*)d_in[8];
    const float* b_hh1  = (const float*)d_in[9];
    const float* W_head = (const float*)d_in[10];

    float* out = (float*)d_out;
    const int M = B_DIM * T_DIM;              // 65536
    float* pre0 = out;                        // d_out doubles as scratch
    float* pre1 = out + (size_t)M * D_DIM;
    float* h1   = (float*)d_ws;               // 64 MB of ws
    float* h2   = h1;

    // pre0 = emb[ids] @ W_ih0^T + (b_ih0 + b_hh0)
    gemm_bt<<<dim3(M / 128, D_DIM / 128), dim3(256), 0, stream>>>(
        nullptr, W_ih0, pre0, b_ih0, b_hh0, ids, emb, M, D_DIM, D_DIM);
    // layer-0 recurrence (MFMA, split-bf16)
    rnn_scan_mfma<<<dim3(8), dim3(512), 0, stream>>>(pre0, W_hh0, h1);
    // pre1 = h1 @ W_ih1^T + (b_ih1 + b_hh1)
    gemm_bt<<<dim3(M / 128, D_DIM / 128), dim3(256), 0, stream>>>(
        h1, W_ih1, pre1, b_ih1, b_hh1, nullptr, nullptr, M, D_DIM, D_DIM);
    // layer-1 recurrence
    rnn_scan_mfma<<<dim3(8), dim3(512), 0, stream>>>(pre1, W_hh1, h2);
    // logits = h2 @ W_head^T
    gemm_bt<<<dim3(M / 128, S_DIM / 128), dim3(256), 0, stream>>>(
        h2, W_head, out, nullptr, nullptr, nullptr, nullptr, M, S_DIM, D_DIM);
}

// Round 4
// 1578.708 us; speedup vs baseline: 1.3260x; 1.3260x over previous
//
#include <hip/hip_runtime.h>
#include <cstdint>
#include <cstddef>

#define D_DIM 256
#define T_DIM 512
#define B_DIM 128
#define S_DIM 512

typedef __attribute__((ext_vector_type(8))) short short8;
typedef __attribute__((ext_vector_type(4))) float f32x4;

// ---------- fp32 tiled GEMM (unchanged): C[M,N] = A @ B^T (+biases) ----------
__global__ __launch_bounds__(256, 2)
void gemm_bt(const float* __restrict__ A, const float* __restrict__ Bm,
             float* __restrict__ C,
             const float* __restrict__ bias1, const float* __restrict__ bias2,
             const int* __restrict__ ids, const float* __restrict__ emb,
             int M, int N, int K)
{
    __shared__ float As[16][128];
    __shared__ float Bs[16][128];
    const int tid = threadIdx.x;
    const int m0 = blockIdx.x * 128;
    const int n0 = blockIdx.y * 128;
    const int tx = tid & 15;
    const int ty = tid >> 4;

    float acc[8][8];
#pragma unroll
    for (int i = 0; i < 8; ++i)
#pragma unroll
        for (int j = 0; j < 8; ++j) acc[i][j] = 0.0f;

    for (int kc = 0; kc < K; kc += 16) {
#pragma unroll
        for (int p = 0; p < 2; ++p) {
            int f   = tid + p * 256;
            int row = f >> 2;
            int kq  = f & 3;
            int gm = m0 + row;
            const float* arow = ids ? (emb + (size_t)ids[gm] * K)
                                    : (A + (size_t)gm * K);
            float4 v = *(const float4*)(arow + kc + kq * 4);
            As[kq * 4 + 0][row] = v.x;
            As[kq * 4 + 1][row] = v.y;
            As[kq * 4 + 2][row] = v.z;
            As[kq * 4 + 3][row] = v.w;
            const float* brow = Bm + (size_t)(n0 + row) * K;
            float4 w = *(const float4*)(brow + kc + kq * 4);
            Bs[kq * 4 + 0][row] = w.x;
            Bs[kq * 4 + 1][row] = w.y;
            Bs[kq * 4 + 2][row] = w.z;
            Bs[kq * 4 + 3][row] = w.w;
        }
        __syncthreads();
#pragma unroll
        for (int k = 0; k < 16; ++k) {
            float a[8], b[8];
            *(float4*)&a[0] = *(const float4*)&As[k][ty * 8];
            *(float4*)&a[4] = *(const float4*)&As[k][ty * 8 + 4];
            *(float4*)&b[0] = *(const float4*)&Bs[k][tx * 8];
            *(float4*)&b[4] = *(const float4*)&Bs[k][tx * 8 + 4];
#pragma unroll
            for (int i = 0; i < 8; ++i)
#pragma unroll
                for (int j = 0; j < 8; ++j) acc[i][j] += a[i] * b[j];
        }
        __syncthreads();
    }

    float bv[8];
#pragma unroll
    for (int j = 0; j < 8; ++j) {
        int gn = n0 + tx * 8 + j;
        float v = 0.0f;
        if (bias1) v += bias1[gn];
        if (bias2) v += bias2[gn];
        bv[j] = v;
    }
#pragma unroll
    for (int i = 0; i < 8; ++i) {
        int gm = m0 + ty * 8 + i;
        float* crow = C + (size_t)gm * N + n0 + tx * 8;
        float4 v0 = make_float4(acc[i][0] + bv[0], acc[i][1] + bv[1],
                                acc[i][2] + bv[2], acc[i][3] + bv[3]);
        float4 v1 = make_float4(acc[i][4] + bv[4], acc[i][5] + bv[5],
                                acc[i][6] + bv[6], acc[i][7] + bv[7]);
        *(float4*)(crow)     = v0;
        *(float4*)(crow + 4) = v1;
    }
}

// ---------- helpers ----------
__device__ inline unsigned short f2bf(float x) {
    unsigned u = __builtin_bit_cast(unsigned, x);
    unsigned r = (u + 0x7fffu + ((u >> 16) & 1u)) >> 16;
    return (unsigned short)r;
}
__device__ inline float bf2f(unsigned short b) {
    unsigned u = ((unsigned)b) << 16;
    return __builtin_bit_cast(float, u);
}
__device__ inline float fast_tanh(float x) {
    float ax = __builtin_fabsf(x);
    float e  = __expf(-2.0f * ax);
    float r  = (1.0f - e) * __builtin_amdgcn_rcpf(1.0f + e);
    return __builtin_copysignf(r, x);
}

// ---------- MFMA Elman scan, one batch row per block ----------
// R3 lesson: MFMA work per block per step is FIXED (every unit needs every h),
// so spread BATCH across blocks: 128 blocks x 1 row -> 128 CUs active (was 8),
// epilogue/block /16, pre-loads /16.  8 waves x 32 units; W_hh hi/lo bf16
// fragments resident in regs (128 VGPR-equiv, AGPR-backed per R3 evidence).
// A-fragment rows m=1..15 are zero: inactive lanes read a shared LDS zero
// region offset by 4 banks -> every ds_read_b128 touches 2 addresses, no
// conflicts, no cndmask.  3-product split (hh + lh + hl) in 6 independent
// accumulator chains.  One barrier/step.
__global__ __launch_bounds__(512) __attribute__((amdgpu_waves_per_eu(2, 2)))
void rnn_scan_mfma(const float* __restrict__ pre, const float* __restrict__ Whh,
                   float* __restrict__ hout)
{
    const int tid  = threadIdx.x;
    const int wave = tid >> 6;
    const int lane = tid & 63;
    const int quad = lane >> 4;
    const int lcol = lane & 15;
    const int b    = blockIdx.x;

    // LDS layout (shorts): Hh[0]@0, Hl[0]@256, Hh[1]@512, Hl[1]@768,
    // pad@1024 (8), Z@1032 (256).  Z is +516 dwords vs Hh[0] => bank +4:
    // lane0's h-read banks and other lanes' zero-read banks are disjoint.
    __shared__ short lds[1288];
    for (int i = tid; i < 1288; i += 512) lds[i] = 0;

    // --- W fragments: B-operand layout, lane holds W[n=.., k=quad*8+j] ---
    short8 wh[2][8], wl[2][8];
#pragma unroll
    for (int tile = 0; tile < 2; ++tile) {
        const int n = wave * 32 + tile * 16 + lcol;
        const float* wr = Whh + (size_t)n * D_DIM + quad * 8;
#pragma unroll
        for (int kt = 0; kt < 8; ++kt) {
            float4 x0 = *(const float4*)(wr + kt * 32);
            float4 x1 = *(const float4*)(wr + kt * 32 + 4);
            float xs[8] = {x0.x, x0.y, x0.z, x0.w, x1.x, x1.y, x1.z, x1.w};
            short8 hi8, lo8;
#pragma unroll
            for (int j = 0; j < 8; ++j) {
                unsigned short h = f2bf(xs[j]);
                unsigned short l = f2bf(xs[j] - bf2f(h));
                hi8[j] = (short)h;
                lo8[j] = (short)l;
            }
            wh[tile][kt] = hi8;
            wl[tile][kt] = lo8;
        }
    }

    // per-lane A-read offsets (shorts): lane lcol==0 reads h, others read Z
    const int O_H[2] = {0, 512};
    const int aoffH0 = (lcol == 0 ? 0   : 1032) + quad * 8;
    const int aoffL0 = (lcol == 0 ? 256 : 1032) + quad * 8;
    const int aoffH1 = (lcol == 0 ? 512 : 1032) + quad * 8;
    const int aoffL1 = (lcol == 0 ? 768 : 1032) + quad * 8;

    const bool active = (lane < 16);           // quad==0; result reg r=0 row m=0
    const int n0 = wave * 32 + lcol;           // tile 0 unit
    const int n1 = n0 + 16;                    // tile 1 unit
    const size_t rowbase = (size_t)b * T_DIM * D_DIM;

    float pv0 = 0.f, pv1 = 0.f;
    if (active) {
        pv0 = pre[rowbase + n0];
        pv1 = pre[rowbase + n1];
    }
    __syncthreads();

    for (int t = 0; t < T_DIM; ++t) {
        // prefetch next step's pre (fully hidden under this step's MFMA phase)
        float nv0 = 0.f, nv1 = 0.f;
        if (active && t + 1 < T_DIM) {
            nv0 = pre[rowbase + (size_t)(t + 1) * D_DIM + n0];
            nv1 = pre[rowbase + (size_t)(t + 1) * D_DIM + n1];
        }

        const int aoH = (t & 1) ? aoffH1 : aoffH0;
        const int aoL = (t & 1) ? aoffL1 : aoffL0;

        f32x4 ahh0 = {0,0,0,0}, ahh1 = {0,0,0,0};
        f32x4 alh0 = {0,0,0,0}, alh1 = {0,0,0,0};
        f32x4 ahl0 = {0,0,0,0}, ahl1 = {0,0,0,0};

        short8 ah = *(const short8*)(lds + aoH);
        short8 al = *(const short8*)(lds + aoL);
#pragma unroll
        for (int kt = 0; kt < 8; ++kt) {
            short8 ahn, aln;
            if (kt < 7) {
                ahn = *(const short8*)(lds + aoH + (kt + 1) * 32);
                aln = *(const short8*)(lds + aoL + (kt + 1) * 32);
            } else {
                ahn = ah; aln = al;
            }
            ahh0 = __builtin_amdgcn_mfma_f32_16x16x32_bf16(ah, wh[0][kt], ahh0, 0, 0, 0);
            ahh1 = __builtin_amdgcn_mfma_f32_16x16x32_bf16(ah, wh[1][kt], ahh1, 0, 0, 0);
            alh0 = __builtin_amdgcn_mfma_f32_16x16x32_bf16(al, wh[0][kt], alh0, 0, 0, 0);
            alh1 = __builtin_amdgcn_mfma_f32_16x16x32_bf16(al, wh[1][kt], alh1, 0, 0, 0);
            ahl0 = __builtin_amdgcn_mfma_f32_16x16x32_bf16(ah, wl[0][kt], ahl0, 0, 0, 0);
            ahl1 = __builtin_amdgcn_mfma_f32_16x16x32_bf16(ah, wl[1][kt], ahl1, 0, 0, 0);
            ah = ahn;
            al = aln;
        }

        // epilogue: only lanes 0..15 hold row m=0 (reg 0)
        if (active) {
            const int wH = O_H[(t + 1) & 1];
            float x0 = ahh0[0] + alh0[0] + ahl0[0] + pv0;
            float x1 = ahh1[0] + alh1[0] + ahl1[0] + pv1;
            float h0 = fast_tanh(x0);
            float h1 = fast_tanh(x1);
            hout[rowbase + (size_t)t * D_DIM + n0] = h0;
            hout[rowbase + (size_t)t * D_DIM + n1] = h1;
            unsigned short h0h = f2bf(h0);
            unsigned short h0l = f2bf(h0 - bf2f(h0h));
            unsigned short h1h = f2bf(h1);
            unsigned short h1l = f2bf(h1 - bf2f(h1h));
            lds[wH + n0]       = (short)h0h;
            lds[wH + n1]       = (short)h1h;
            lds[wH + 256 + n0] = (short)h0l;
            lds[wH + 256 + n1] = (short)h1l;
        }
        pv0 = nv0;
        pv1 = nv1;
        __syncthreads();
    }
}

extern "C" void kernel_launch(void* const* d_in, const int* in_sizes, int n_in,
                              void* d_out, int out_size, void* d_ws, size_t ws_size,
                              hipStream_t stream)
{
    const int*   ids    = (const int*)  d_in[0];
    const float* emb    = (const float*)d_in[1];
    const float* W_ih0  = (const float*)d_in[2];
    const float* W_hh0  = (const float*)d_in[3];
    const float* b_ih0  = (const float*)d_in[4];
    const float* b_hh0  = (const float*)d_in[5];
    const float* W_ih1  = (const float*)d_in[6];
    const float* W_hh1  = (const float*)d_in[7];
    const float* b_ih1  = (const float*)d_in[8];
    const float* b_hh1  = (const float*)d_in[9];
    const float* W_head = (const float*)d_in[10];

    float* out = (float*)d_out;
    const int M = B_DIM * T_DIM;              // 65536
    float* pre0 = out;                        // d_out doubles as scratch
    float* pre1 = out + (size_t)M * D_DIM;
    float* h1   = (float*)d_ws;               // 64 MB of ws
    float* h2   = h1;

    // pre0 = emb[ids] @ W_ih0^T + (b_ih0 + b_hh0)
    gemm_bt<<<dim3(M / 128, D_DIM / 128), dim3(256), 0, stream>>>(
        nullptr, W_ih0, pre0, b_ih0, b_hh0, ids, emb, M, D_DIM, D_DIM);
    // layer-0 recurrence (MFMA, split-bf16, 1 batch row per block)
    rnn_scan_mfma<<<dim3(B_DIM), dim3(512), 0, stream>>>(pre0, W_hh0, h1);
    // pre1 = h1 @ W_ih1^T + (b_ih1 + b_hh1)
    gemm_bt<<<dim3(M / 128, D_DIM / 128), dim3(256), 0, stream>>>(
        h1, W_ih1, pre1, b_ih1, b_hh1, nullptr, nullptr, M, D_DIM, D_DIM);
    // layer-1 recurrence
    rnn_scan_mfma<<<dim3(B_DIM), dim3(512), 0, stream>>>(pre1, W_hh1, h2);
    // logits = h2 @ W_head^T
    gemm_bt<<<dim3(M / 128, S_DIM / 128), dim3(256), 0, stream>>>(
        h2, W_head, out, nullptr, nullptr, nullptr, nullptr, M, S_DIM, D_DIM);
}